// Round 20
// baseline (196.976 us; speedup 1.0000x reference)
//
#include <hip/hip_runtime.h>
#include <hip/hip_bf16.h>

#define NROWS 16384
#define DIM   256
#define SEGS  8
#define BN    128                     // staged tile: 128 cols x 256 k (fp8) = 32 KB
#define NT    ((NROWS / SEGS) / BN)   // 16 tiles per segment
#define INVT  14.285714285714286f
#define C1f   20.60992915555662f      // log2(e)/0.07 ; A is pre-scaled by this
#define LN2f  0.6931471805599453f

typedef __attribute__((ext_vector_type(8)))  int   int8v;    // fp8 A/B fragment (32 bytes)
typedef __attribute__((ext_vector_type(4)))  float f32x4;    // 16x16 MFMA accumulator

#define SCALE1 0x7F7F7F7F   // E8M0 = 1.0 in every byte (opsel-proof)

// Kernel 1: L2-normalize (fp32); emit fp8 e4m3 A (row-major, xC1) and fp8 B in the
// LINEAR DMA staging layout, plus exact fp32 diagonal. One wave per row.
// B layout (16B chunks): chunk(col,kcb) = (col>>7)*2048 + ((col>>6)&1)*1024
//                                        + kcb*64 + (col&63)
__global__ __launch_bounds__(256) void norm_diag_kernel(
    const float* __restrict__ fl, const float* __restrict__ fg,
    unsigned char* __restrict__ A, unsigned char* __restrict__ B,
    float* __restrict__ diag, float* __restrict__ out)
{
    int tid  = threadIdx.x;
    int wave = tid >> 6, lane = tid & 63;
    int row  = blockIdx.x * 4 + wave;
    if (blockIdx.x == 0 && tid == 0) out[0] = 0.0f;   // zero accumulator for final atomicAdd

    float4 xl = ((const float4*)(fl + (size_t)row * DIM))[lane];
    float4 xg = ((const float4*)(fg + (size_t)row * DIM))[lane];
    float ssl = xl.x*xl.x + xl.y*xl.y + xl.z*xl.z + xl.w*xl.w;
    float ssg = xg.x*xg.x + xg.y*xg.y + xg.z*xg.z + xg.w*xg.w;
    for (int m = 1; m < 64; m <<= 1) {
        ssl += __shfl_xor(ssl, m, 64);
        ssg += __shfl_xor(ssg, m, 64);
    }
    float il = 1.0f / fmaxf(sqrtf(ssl), 1e-12f);
    float ig = 1.0f / fmaxf(sqrtf(ssg), 1e-12f);
    float nl0 = xl.x*il, nl1 = xl.y*il, nl2 = xl.z*il, nl3 = xl.w*il;
    float ng0 = xg.x*ig, ng1 = xg.y*ig, ng2 = xg.z*ig, ng3 = xg.w*ig;

    int pa = __builtin_amdgcn_cvt_pk_fp8_f32(nl0 * C1f, nl1 * C1f, 0, false);
    pa     = __builtin_amdgcn_cvt_pk_fp8_f32(nl2 * C1f, nl3 * C1f, pa, true);
    int pb = __builtin_amdgcn_cvt_pk_fp8_f32(ng0, ng1, 0, false);
    pb     = __builtin_amdgcn_cvt_pk_fp8_f32(ng2, ng3, pb, true);
    ((int*)(A + (size_t)row * DIM))[lane] = pa;   // A row-major

    {   // B in linear staging layout
        int kcb = lane >> 2;          // 16B chunk along K (0..15)
        int b4  = lane & 3;           // dword within chunk
        unsigned chunk = (unsigned)((row >> 7) * 2048 + ((row >> 6) & 1) * 1024
                                    + kcb * 64 + (row & 63));
        ((int*)B)[chunk * 4 + b4] = pb;
    }

    float d = nl0*ng0 + nl1*ng1 + nl2*ng2 + nl3*ng3;   // exact fp32 diagonal
    for (int m = 1; m < 64; m <<= 1) d += __shfl_xor(d, m, 64);
    if (lane == 0) diag[row] = d;
}

// Kernel 2: fused sim-GEMM + fixed-max sumexp, MX-fp8 16x16x128.
// R19 frame (DMA prefetch, one barrier/tile, ping-pong acc, deferred epilogue,
// imm-offset LDS reads, direct tuple loads) with the MFMA shape switched from
// 32x32x64 (2 dependent chains of depth 4) to 16x16x128 (8 independent chains
// of depth 2) -- same FLOP rate, much better matrix-pipe fill.
// Fragments: A[m=l15][k=quad*32+j]; C/D col=l15, row=quad*4+r (HW-verified 16x16).
__global__ __launch_bounds__(256, 2) void sim_lse_kernel(
    const unsigned char* __restrict__ A, const unsigned char* __restrict__ B,
    float* __restrict__ lpart)
{
    __shared__ __align__(16) unsigned char bt[2 * BN * DIM];   // 2 x 32 KB double buffer

    int tid  = threadIdx.x;
    int lane = tid & 63;
    int l15  = lane & 15, quad = lane >> 4;
    int wave = tid >> 6;
    int seg  = blockIdx.x;
    int rowBase = blockIdx.y * 256 + wave * 64;

    // LDS read base: addr = vb + bufo + (cs*256 + ks*8192 + {0,1024}) immediates
    unsigned vb = (unsigned)(l15 * 16 + quad * 2048);

    // Preload A fragments: lane(l15,quad) holds A[m=rs*16+l15][k = ks*128 + quad*32 + 0..31]
    int8v af[4][2];
#pragma unroll
    for (int rs = 0; rs < 4; ++rs) {
        const unsigned char* ap = A + (size_t)(rowBase + rs*16 + l15) * DIM + quad * 32;
#pragma unroll
        for (int ks = 0; ks < 2; ++ks) {
            ((int4*)&af[rs][ks])[0] = *(const int4*)(ap + ks * 128);
            ((int4*)&af[rs][ks])[1] = *(const int4*)(ap + ks * 128 + 16);
        }
    }

    f32x4 lv[4];          // per row-set column-sum accumulators (16 regs)
    f32x4 Z4;
    f32x4 accA[4][2], accB[4][2];   // ping-pong unit accumulators (32+32 regs)
#pragma unroll
    for (int rs = 0; rs < 4; ++rs) {
#pragma unroll
        for (int r = 0; r < 4; ++r) lv[rs][r] = -2.0f;   // compensate dummy epi (2 col-sets x exp2(0))
#pragma unroll
        for (int cs = 0; cs < 2; ++cs)
#pragma unroll
            for (int r = 0; r < 4; ++r) { accB[rs][cs][r] = 0.0f; }
    }
#pragma unroll
    for (int r = 0; r < 4; ++r) Z4[r] = 0.0f;

    int T0 = seg * NT;

    auto stage = [&](int T, unsigned bufo) {
        const unsigned char* g = B + (size_t)T * (BN * DIM) + (wave * 512 + lane) * 16;
        unsigned lo = bufo + (unsigned)(wave * 512) * 16;
#pragma unroll
        for (int j = 0; j < 8; ++j) {
            __builtin_amdgcn_global_load_lds(
                (const __attribute__((address_space(1))) unsigned int*)(g + j * 1024),
                (__attribute__((address_space(3))) unsigned int*)&bt[lo + j * 1024],
                16, 0, 0);
        }
    };

    // One 64x32 unit: 8 ds_read_b128 + 16 MFMAs (8 indep ks=0, then 8 ks=1)
    auto chain = [&](f32x4 (&ac)[4][2], unsigned ab, unsigned offc) {
        int8v bf[2][2];
#pragma unroll
        for (int cs = 0; cs < 2; ++cs)
#pragma unroll
            for (int ks = 0; ks < 2; ++ks) {
                unsigned base = ab + offc + (unsigned)cs * 256u + (unsigned)ks * 8192u;
                ((int4*)&bf[cs][ks])[0] = *(const int4*)&bt[base];
                ((int4*)&bf[cs][ks])[1] = *(const int4*)&bt[base + 1024u];
            }
#pragma unroll
        for (int rs = 0; rs < 4; ++rs)
#pragma unroll
            for (int cs = 0; cs < 2; ++cs)
                ac[rs][cs] = __builtin_amdgcn_mfma_scale_f32_16x16x128_f8f6f4(
                    af[rs][0], bf[cs][0], Z4, 0, 0, 0, SCALE1, 0, SCALE1);
#pragma unroll
        for (int rs = 0; rs < 4; ++rs)
#pragma unroll
            for (int cs = 0; cs < 2; ++cs)
                ac[rs][cs] = __builtin_amdgcn_mfma_scale_f32_16x16x128_f8f6f4(
                    af[rs][1], bf[cs][1], ac[rs][cs], 0, 0, 0, SCALE1, 0, SCALE1);
    };

    auto epi = [&](f32x4 (&ac)[4][2]) {
#pragma unroll
        for (int rs = 0; rs < 4; ++rs)
#pragma unroll
            for (int cs = 0; cs < 2; ++cs)
#pragma unroll
                for (int r = 0; r < 4; ++r)
                    lv[rs][r] += __builtin_amdgcn_exp2f(ac[rs][cs][r]);
    };

    stage(T0, 0);

    for (int t = 0; t < NT; ++t) {
        unsigned bufo = (t & 1) ? (unsigned)(BN * DIM) : 0u;
        __syncthreads();   // drains own tile-t DMA (in flight a full tile), syncs waves

        if (t + 1 < NT)
            stage(T0 + t + 1, (t & 1) ? 0u : (unsigned)(BN * DIM));

        unsigned ab = vb + bufo;
        chain(accA, ab, 0u);      epi(accB);
        chain(accB, ab, 512u);    epi(accA);
        chain(accA, ab, 16384u);  epi(accB);
        chain(accB, ab, 16896u);  epi(accA);
    }
    epi(accB);   // final unit

    // Sum across the 16 column-lanes (xor 1,2,4,8 stays within each quad group)
#pragma unroll
    for (int rs = 0; rs < 4; ++rs)
#pragma unroll
        for (int r = 0; r < 4; ++r) {
            float v = lv[rs][r];
            v += __shfl_xor(v, 1, 64);
            v += __shfl_xor(v, 2, 64);
            v += __shfl_xor(v, 4, 64);
            v += __shfl_xor(v, 8, 64);
            lv[rs][r] = v;
        }
    if (l15 == 0) {
#pragma unroll
        for (int rs = 0; rs < 4; ++rs)
#pragma unroll
            for (int r = 0; r < 4; ++r) {
                int row = rowBase + rs*16 + quad*4 + r;   // C/D: row=quad*4+r (verified)
                lpart[(size_t)seg * NROWS + row] = lv[rs][r];
            }
    }
}

// Kernel 3: loss_i = -invT*diag_i + ln2*log2(sum_seg l_part), then mean via atomicAdd.
__global__ __launch_bounds__(256) void reduce_kernel(
    const float* __restrict__ lpart, const float* __restrict__ diag,
    float* __restrict__ out)
{
    __shared__ float sm[4];
    int gtid = blockIdx.x * 256 + threadIdx.x;
    float s = 0.0f;
    for (int row = gtid; row < NROWS; row += 32 * 256) {
        float t = 0.0f;
#pragma unroll
        for (int g = 0; g < SEGS; ++g) t += lpart[(size_t)g * NROWS + row];
        s += LN2f * log2f(t) - INVT * diag[row];
    }
    for (int m = 1; m < 64; m <<= 1) s += __shfl_xor(s, m, 64);
    int wave = threadIdx.x >> 6, lane = threadIdx.x & 63;
    if (lane == 0) sm[wave] = s;
    __syncthreads();
    if (threadIdx.x == 0) {
        float tot = sm[0] + sm[1] + sm[2] + sm[3];
        atomicAdd(out, tot * (1.0f / NROWS));
    }
}

extern "C" void kernel_launch(void* const* d_in, const int* in_sizes, int n_in,
                              void* d_out, int out_size, void* d_ws, size_t ws_size,
                              hipStream_t stream) {
    const float* fl = (const float*)d_in[0];
    const float* fg = (const float*)d_in[1];
    float* out = (float*)d_out;

    char* ws = (char*)d_ws;
    unsigned char* A = (unsigned char*)ws;                         // 16384*256 = 4 MB
    unsigned char* B = A + (size_t)NROWS * DIM;                    // 4 MB (staging layout)
    float* diag  = (float*)(ws + 2 * (size_t)NROWS * DIM);         // 64 KB
    float* lpart = diag + NROWS;                                   // SEGS*N*4 = 512 KB

    norm_diag_kernel<<<NROWS / 4, 256, 0, stream>>>(fl, fg, A, B, diag, out);
    sim_lse_kernel<<<dim3(SEGS, NROWS / 256), 256, 0, stream>>>(A, B, lpart);
    reduce_kernel<<<32, 256, 0, stream>>>(lpart, diag, out);
}

// Round 21
// 144.047 us; speedup vs baseline: 1.3674x; 1.3674x over previous
//
#include <hip/hip_runtime.h>
#include <hip/hip_bf16.h>

#define NROWS 16384
#define DIM   256
#define SEGS  8
#define BN    64                      // staged tile: 64 cols x 256 k (fp8) = 16 KB
#define NT    ((NROWS / SEGS) / BN)   // 32 tiles per segment
#define INVT  14.285714285714286f
#define C1f   20.60992915555662f      // log2(e)/0.07 ; A is pre-scaled by this
#define LN2f  0.6931471805599453f

typedef __attribute__((ext_vector_type(8)))  int   int8v;    // fp8 A/B fragment (32 bytes)
typedef __attribute__((ext_vector_type(16))) float f32x16;   // 32x32 MFMA accumulator

#define SCALE1 0x7F7F7F7F   // E8M0 = 1.0 in every byte (opsel-proof)

// Kernel 1: L2-normalize (fp32); emit fp8 e4m3 A (row-major, xC1) and fp8 B in the
// LINEAR DMA staging layout, plus exact fp32 diagonal. One wave per row.
// B layout (16B chunks): chunk(col,kcb) = (col>>6)*1024 + kcb*64 + (col&63)
__global__ __launch_bounds__(256) void norm_diag_kernel(
    const float* __restrict__ fl, const float* __restrict__ fg,
    unsigned char* __restrict__ A, unsigned char* __restrict__ B,
    float* __restrict__ diag, float* __restrict__ out)
{
    int tid  = threadIdx.x;
    int wave = tid >> 6, lane = tid & 63;
    int row  = blockIdx.x * 4 + wave;
    if (blockIdx.x == 0 && tid == 0) out[0] = 0.0f;   // zero accumulator for final atomicAdd

    float4 xl = ((const float4*)(fl + (size_t)row * DIM))[lane];
    float4 xg = ((const float4*)(fg + (size_t)row * DIM))[lane];
    float ssl = xl.x*xl.x + xl.y*xl.y + xl.z*xl.z + xl.w*xl.w;
    float ssg = xg.x*xg.x + xg.y*xg.y + xg.z*xg.z + xg.w*xg.w;
    for (int m = 1; m < 64; m <<= 1) {
        ssl += __shfl_xor(ssl, m, 64);
        ssg += __shfl_xor(ssg, m, 64);
    }
    float il = 1.0f / fmaxf(sqrtf(ssl), 1e-12f);
    float ig = 1.0f / fmaxf(sqrtf(ssg), 1e-12f);
    float nl0 = xl.x*il, nl1 = xl.y*il, nl2 = xl.z*il, nl3 = xl.w*il;
    float ng0 = xg.x*ig, ng1 = xg.y*ig, ng2 = xg.z*ig, ng3 = xg.w*ig;

    int pa = __builtin_amdgcn_cvt_pk_fp8_f32(nl0 * C1f, nl1 * C1f, 0, false);
    pa     = __builtin_amdgcn_cvt_pk_fp8_f32(nl2 * C1f, nl3 * C1f, pa, true);
    int pb = __builtin_amdgcn_cvt_pk_fp8_f32(ng0, ng1, 0, false);
    pb     = __builtin_amdgcn_cvt_pk_fp8_f32(ng2, ng3, pb, true);
    ((int*)(A + (size_t)row * DIM))[lane] = pa;   // A row-major

    {   // B in linear staging layout (BN=64 tiles)
        int kcb = lane >> 2;          // 16B chunk along K (0..15)
        int b4  = lane & 3;           // dword within chunk
        unsigned chunk = (unsigned)((row >> 6) * 1024 + kcb * 64 + (row & 63));
        ((int*)B)[chunk * 4 + b4] = pb;
    }

    float d = nl0*ng0 + nl1*ng1 + nl2*ng2 + nl3*ng3;   // exact fp32 diagonal
    for (int m = 1; m < 64; m <<= 1) d += __shfl_xor(d, m, 64);
    if (lane == 0) diag[row] = d;
}

// Kernel 2: fused sim-GEMM + fixed-max sumexp, MX-fp8 32x32x64 at 4 waves/SIMD.
// Wave tile halved to 32 rows x 64 cols so the whole wave fits a 128-reg budget
// BY DESIGN (af 32 + acc ping-pong 32 + lv 16 + Z 16 + bf 8 + misc ~= 119):
// narrow bf liveness (load fragment -> MFMA immediately; 4-wave TLP hides the
// lgkm latency instead of intra-wave ILP). BN=64 dbuf (32 KB) x 4 blocks/CU
// = 128 KB LDS. Grid (8,128) = 1024 blocks = 4 blocks/CU. Four independent-
// phase waves/SIMD supply the MFMA<->VALU overlap intra-wave attempts couldn't.
__global__ __launch_bounds__(256, 4) void sim_lse_kernel(
    const unsigned char* __restrict__ A, const unsigned char* __restrict__ B,
    float* __restrict__ lpart)
{
    __shared__ __align__(16) unsigned char bt[2 * BN * DIM];   // 2 x 16 KB double buffer

    int tid  = threadIdx.x;
    int lane = tid & 63;
    int l31  = lane & 31, half = lane >> 5;
    int wave = tid >> 6;
    int seg  = blockIdx.x;
    int rowBase = blockIdx.y * 128 + wave * 32;

    unsigned vb = (unsigned)(l31 * 16 + half * 2048);   // LDS read base

    // Preload A fragments: lane(l31,half) holds A[m=l31][k = kk*64 + half*32 + 0..31]
    int8v af[4];
    {
        const unsigned char* ap = A + (size_t)(rowBase + l31) * DIM + half * 32;
#pragma unroll
        for (int kk = 0; kk < 4; ++kk) {
            ((int4*)&af[kk])[0] = *(const int4*)(ap + kk * 64);
            ((int4*)&af[kk])[1] = *(const int4*)(ap + kk * 64 + 16);
        }
    }

    f32x16 lv, Z, accA, accB;
#pragma unroll
    for (int r = 0; r < 16; ++r) {
        lv[r] = -1.0f;     // compensate the one dummy epilogue
        Z[r] = 0.0f;
        accB[r] = 0.0f;    // dummy-epilogue source
    }

    int T0 = seg * NT;

    // Stage one 16 KB tile (1024 chunks); each thread moves 4 chunks
    auto stage = [&](int T, unsigned bufo) {
        const unsigned char* g = B + (size_t)T * (BN * DIM) + (unsigned)tid * 16;
        unsigned lo = bufo + (unsigned)tid * 16;
#pragma unroll
        for (int j = 0; j < 4; ++j) {
            __builtin_amdgcn_global_load_lds(
                (const __attribute__((address_space(1))) unsigned int*)(g + j * 4096),
                (__attribute__((address_space(3))) unsigned int*)&bt[lo + j * 4096],
                16, 0, 0);
        }
    };

    // One 32x32 unit: 4x (2 ds_read_b128 -> MFMA), narrow bf liveness (8 regs)
    auto chain = [&](f32x16 &ac, unsigned ab, unsigned offc) {
        {
            int8v bf;
            ((int4*)&bf)[0] = *(const int4*)&bt[ab + offc];
            ((int4*)&bf)[1] = *(const int4*)&bt[ab + offc + 1024u];
            ac = __builtin_amdgcn_mfma_scale_f32_32x32x64_f8f6f4(
                af[0], bf, Z, 0, 0, 0, SCALE1, 0, SCALE1);
        }
#pragma unroll
        for (int kk = 1; kk < 4; ++kk) {
            int8v bf;
            ((int4*)&bf)[0] = *(const int4*)&bt[ab + offc + (unsigned)kk * 4096u];
            ((int4*)&bf)[1] = *(const int4*)&bt[ab + offc + (unsigned)kk * 4096u + 1024u];
            ac = __builtin_amdgcn_mfma_scale_f32_32x32x64_f8f6f4(
                af[kk], bf, ac, 0, 0, 0, SCALE1, 0, SCALE1);
        }
    };

    auto epi = [&](f32x16 &ac) {
#pragma unroll
        for (int r = 0; r < 16; ++r)
            lv[r] += __builtin_amdgcn_exp2f(ac[r]);
    };

    stage(T0, 0);

    for (int t = 0; t < NT; ++t) {
        unsigned bufo = (t & 1) ? (unsigned)(BN * DIM) : 0u;
        __syncthreads();   // drains own tile-t DMA (in flight a full tile), syncs waves

        if (t + 1 < NT)
            stage(T0 + t + 1, (t & 1) ? 0u : (unsigned)(BN * DIM));

        unsigned ab = vb + bufo;
        chain(accA, ab, 0u);    epi(accB);   // cols 0-31 (dummy epi at t=0)
        chain(accB, ab, 512u);  epi(accA);   // cols 32-63
    }
    epi(accB);   // final unit

    // Sum across the 32 column-lanes
#pragma unroll
    for (int r = 0; r < 16; ++r) {
        float v = lv[r];
        v += __shfl_xor(v, 1, 64);
        v += __shfl_xor(v, 2, 64);
        v += __shfl_xor(v, 4, 64);
        v += __shfl_xor(v, 8, 64);
        v += __shfl_xor(v, 16, 64);
        lv[r] = v;
    }
    if (l31 == 0) {
#pragma unroll
        for (int r = 0; r < 16; ++r) {
            int row = rowBase + (r & 3) + 8*(r >> 2) + 4*half;
            lpart[(size_t)seg * NROWS + row] = lv[r];
        }
    }
}

// Kernel 3: loss_i = -invT*diag_i + ln2*log2(sum_seg l_part), then mean via atomicAdd.
__global__ __launch_bounds__(256) void reduce_kernel(
    const float* __restrict__ lpart, const float* __restrict__ diag,
    float* __restrict__ out)
{
    __shared__ float sm[4];
    int gtid = blockIdx.x * 256 + threadIdx.x;
    float s = 0.0f;
    for (int row = gtid; row < NROWS; row += 32 * 256) {
        float t = 0.0f;
#pragma unroll
        for (int g = 0; g < SEGS; ++g) t += lpart[(size_t)g * NROWS + row];
        s += LN2f * log2f(t) - INVT * diag[row];
    }
    for (int m = 1; m < 64; m <<= 1) s += __shfl_xor(s, m, 64);
    int wave = threadIdx.x >> 6, lane = threadIdx.x & 63;
    if (lane == 0) sm[wave] = s;
    __syncthreads();
    if (threadIdx.x == 0) {
        float tot = sm[0] + sm[1] + sm[2] + sm[3];
        atomicAdd(out, tot * (1.0f / NROWS));
    }
}

extern "C" void kernel_launch(void* const* d_in, const int* in_sizes, int n_in,
                              void* d_out, int out_size, void* d_ws, size_t ws_size,
                              hipStream_t stream) {
    const float* fl = (const float*)d_in[0];
    const float* fg = (const float*)d_in[1];
    float* out = (float*)d_out;

    char* ws = (char*)d_ws;
    unsigned char* A = (unsigned char*)ws;                         // 16384*256 = 4 MB
    unsigned char* B = A + (size_t)NROWS * DIM;                    // 4 MB (staging layout)
    float* diag  = (float*)(ws + 2 * (size_t)NROWS * DIM);         // 64 KB
    float* lpart = diag + NROWS;                                   // SEGS*N*4 = 512 KB

    norm_diag_kernel<<<NROWS / 4, 256, 0, stream>>>(fl, fg, A, B, diag, out);
    sim_lse_kernel<<<dim3(SEGS, NROWS / 128), 256, 0, stream>>>(A, B, lpart);
    reduce_kernel<<<32, 256, 0, stream>>>(lpart, diag, out);
}

// Round 22
// 138.848 us; speedup vs baseline: 1.4186x; 1.0374x over previous
//
#include <hip/hip_runtime.h>
#include <hip/hip_bf16.h>

#define NROWS 16384
#define DIM   256
#define SEGS  8
#define BN    128                     // staged tile: 128 cols x 256 k (fp8) = 32 KB
#define NT    ((NROWS / SEGS) / BN)   // 16 tiles per segment
#define INVT  14.285714285714286f
#define C1f   20.60992915555662f      // log2(e)/0.07 ; A is pre-scaled by this
#define LN2f  0.6931471805599453f

typedef __attribute__((ext_vector_type(8)))  int   int8v;    // fp8 A/B fragment (32 bytes)
typedef __attribute__((ext_vector_type(16))) float f32x16;   // 32x32 MFMA accumulator

#define SCALE1 0x7F7F7F7F   // E8M0 = 1.0 in every byte (opsel-proof)

// Kernel 1: L2-normalize (fp32); emit fp8 e4m3 A (row-major, xC1) and fp8 B in the
// LINEAR DMA staging layout, plus exact fp32 diagonal. One wave per row.
// B layout (16B chunks): chunk(col,kcb) = (col>>7)*2048 + ((col>>6)&1)*1024
//                                        + kcb*64 + (col&63)
__global__ __launch_bounds__(256) void norm_diag_kernel(
    const float* __restrict__ fl, const float* __restrict__ fg,
    unsigned char* __restrict__ A, unsigned char* __restrict__ B,
    float* __restrict__ diag, float* __restrict__ out)
{
    int tid  = threadIdx.x;
    int wave = tid >> 6, lane = tid & 63;
    int row  = blockIdx.x * 4 + wave;
    if (blockIdx.x == 0 && tid == 0) out[0] = 0.0f;   // zero accumulator for final atomicAdd

    float4 xl = ((const float4*)(fl + (size_t)row * DIM))[lane];
    float4 xg = ((const float4*)(fg + (size_t)row * DIM))[lane];
    float ssl = xl.x*xl.x + xl.y*xl.y + xl.z*xl.z + xl.w*xl.w;
    float ssg = xg.x*xg.x + xg.y*xg.y + xg.z*xg.z + xg.w*xg.w;
    for (int m = 1; m < 64; m <<= 1) {
        ssl += __shfl_xor(ssl, m, 64);
        ssg += __shfl_xor(ssg, m, 64);
    }
    float il = 1.0f / fmaxf(sqrtf(ssl), 1e-12f);
    float ig = 1.0f / fmaxf(sqrtf(ssg), 1e-12f);
    float nl0 = xl.x*il, nl1 = xl.y*il, nl2 = xl.z*il, nl3 = xl.w*il;
    float ng0 = xg.x*ig, ng1 = xg.y*ig, ng2 = xg.z*ig, ng3 = xg.w*ig;

    int pa = __builtin_amdgcn_cvt_pk_fp8_f32(nl0 * C1f, nl1 * C1f, 0, false);
    pa     = __builtin_amdgcn_cvt_pk_fp8_f32(nl2 * C1f, nl3 * C1f, pa, true);
    int pb = __builtin_amdgcn_cvt_pk_fp8_f32(ng0, ng1, 0, false);
    pb     = __builtin_amdgcn_cvt_pk_fp8_f32(ng2, ng3, pb, true);
    ((int*)(A + (size_t)row * DIM))[lane] = pa;   // A row-major

    {   // B in linear staging layout
        int kcb = lane >> 2;          // 16B chunk along K (0..15)
        int b4  = lane & 3;           // dword within chunk
        unsigned chunk = (unsigned)((row >> 7) * 2048 + ((row >> 6) & 1) * 1024
                                    + kcb * 64 + (row & 63));
        ((int*)B)[chunk * 4 + b4] = pb;
    }

    float d = nl0*ng0 + nl1*ng1 + nl2*ng2 + nl3*ng3;   // exact fp32 diagonal
    for (int m = 1; m < 64; m <<= 1) d += __shfl_xor(d, m, 64);
    if (lane == 0) diag[row] = d;
}

// Kernel 2: fused sim-GEMM + fixed-max sumexp, MX-fp8 32x32x64.
// R19 frame (DMA prefetch, one barrier/tile, ping-pong acc, imm-offset LDS
// reads, direct tuple loads; 66 us) with ONE reorder: per unit the issue
// order is  loadbf (8 ds_read) -> epi(prev unit, 256 cyc indep VALU) ->
// mfmas (8 MFMA)  -- the epilogue now fills the lgkm wait between the reads
// and their consuming MFMAs instead of queuing behind them.
__global__ __launch_bounds__(256, 2) void sim_lse_kernel(
    const unsigned char* __restrict__ A, const unsigned char* __restrict__ B,
    float* __restrict__ lpart)
{
    __shared__ __align__(16) unsigned char bt[2 * BN * DIM];   // 2 x 32 KB double buffer

    int tid  = threadIdx.x;
    int lane = tid & 63;
    int l31  = lane & 31, half = lane >> 5;
    int wave = tid >> 6;
    int seg  = blockIdx.x;
    int rowBase = blockIdx.y * 256 + wave * 64;

    unsigned vb = (unsigned)(l31 * 16 + half * 2048);   // LDS read base

    // Preload A fragments: direct 16B loads into tuple halves
    int8v af[2][4];
#pragma unroll
    for (int s = 0; s < 2; ++s) {
        const unsigned char* ap = A + (size_t)(rowBase + s*32 + l31) * DIM + half * 32;
#pragma unroll
        for (int kk = 0; kk < 4; ++kk) {
            ((int4*)&af[s][kk])[0] = *(const int4*)(ap + kk * 64);
            ((int4*)&af[s][kk])[1] = *(const int4*)(ap + kk * 64 + 16);
        }
    }

    f32x16 lv[2];
    f32x16 Z;
    f32x16 accA[2], accB[2];
#pragma unroll
    for (int r = 0; r < 16; ++r) {
        lv[0][r] = -1.0f; lv[1][r] = -1.0f;   // compensate the one dummy epilogue
        Z[r] = 0.0f;
        accB[0][r] = 0.0f; accB[1][r] = 0.0f; // dummy-epilogue source
    }

    int T0 = seg * NT;

    auto stage = [&](int T, unsigned bufo) {
        const unsigned char* g = B + (size_t)T * (BN * DIM) + (wave * 512 + lane) * 16;
        unsigned lo = bufo + (unsigned)(wave * 512) * 16;
#pragma unroll
        for (int j = 0; j < 8; ++j) {
            __builtin_amdgcn_global_load_lds(
                (const __attribute__((address_space(1))) unsigned int*)(g + j * 1024),
                (__attribute__((address_space(3))) unsigned int*)&bt[lo + j * 1024],
                16, 0, 0);
        }
    };

    // Issue the 8 ds_read_b128 for one unit (no use yet -> no wait here)
    auto loadbf = [&](int8v (&bf)[4], unsigned ab, unsigned offc) {
#pragma unroll
        for (int kk = 0; kk < 4; ++kk) {
            ((int4*)&bf[kk])[0] = *(const int4*)&bt[ab + offc + (unsigned)kk * 4096u];
            ((int4*)&bf[kk])[1] = *(const int4*)&bt[ab + offc + (unsigned)kk * 4096u + 1024u];
        }
    };

    // 8 MFMAs consuming a loaded fragment set
    auto mfmas = [&](f32x16 (&ac)[2], int8v (&bf)[4]) {
        ac[0] = __builtin_amdgcn_mfma_scale_f32_32x32x64_f8f6f4(
            af[0][0], bf[0], Z, 0, 0, 0, SCALE1, 0, SCALE1);
        ac[1] = __builtin_amdgcn_mfma_scale_f32_32x32x64_f8f6f4(
            af[1][0], bf[0], Z, 0, 0, 0, SCALE1, 0, SCALE1);
#pragma unroll
        for (int kk = 1; kk < 4; ++kk) {
            ac[0] = __builtin_amdgcn_mfma_scale_f32_32x32x64_f8f6f4(
                af[0][kk], bf[kk], ac[0], 0, 0, 0, SCALE1, 0, SCALE1);
            ac[1] = __builtin_amdgcn_mfma_scale_f32_32x32x64_f8f6f4(
                af[1][kk], bf[kk], ac[1], 0, 0, 0, SCALE1, 0, SCALE1);
        }
    };

    auto epi = [&](f32x16 (&ac)[2]) {
#pragma unroll
        for (int s = 0; s < 2; ++s) {
            f32x16 e;
#pragma unroll
            for (int r = 0; r < 16; ++r)
                e[r] = __builtin_amdgcn_exp2f(ac[s][r]);
            lv[s] += e;
        }
    };

    stage(T0, 0);

    int8v bf[4];   // single fragment set, reused per unit (narrow liveness)

    for (int t = 0; t < NT; ++t) {
        unsigned bufo = (t & 1) ? (unsigned)(BN * DIM) : 0u;
        __syncthreads();   // drains own tile-t DMA (in flight a full tile), syncs waves

        if (t + 1 < NT)
            stage(T0 + t + 1, (t & 1) ? 0u : (unsigned)(BN * DIM));

        unsigned ab = vb + bufo;
        loadbf(bf, ab, 0u);      epi(accB);  mfmas(accA, bf);
        loadbf(bf, ab, 512u);    epi(accA);  mfmas(accB, bf);
        loadbf(bf, ab, 16384u);  epi(accB);  mfmas(accA, bf);
        loadbf(bf, ab, 16896u);  epi(accA);  mfmas(accB, bf);
    }
    epi(accB);   // final unit

    // Sum across the 32 column-lanes
#pragma unroll
    for (int s = 0; s < 2; ++s)
#pragma unroll
        for (int r = 0; r < 16; ++r) {
            float v = lv[s][r];
            v += __shfl_xor(v, 1, 64);
            v += __shfl_xor(v, 2, 64);
            v += __shfl_xor(v, 4, 64);
            v += __shfl_xor(v, 8, 64);
            v += __shfl_xor(v, 16, 64);
            lv[s][r] = v;
        }
    if (l31 == 0) {
#pragma unroll
        for (int s = 0; s < 2; ++s)
#pragma unroll
            for (int r = 0; r < 16; ++r) {
                int row = rowBase + s*32 + (r & 3) + 8*(r >> 2) + 4*half;
                lpart[(size_t)seg * NROWS + row] = lv[s][r];
            }
    }
}

// Kernel 3: loss_i = -invT*diag_i + ln2*log2(sum_seg l_part), then mean via atomicAdd.
__global__ __launch_bounds__(256) void reduce_kernel(
    const float* __restrict__ lpart, const float* __restrict__ diag,
    float* __restrict__ out)
{
    __shared__ float sm[4];
    int gtid = blockIdx.x * 256 + threadIdx.x;
    float s = 0.0f;
    for (int row = gtid; row < NROWS; row += 32 * 256) {
        float t = 0.0f;
#pragma unroll
        for (int g = 0; g < SEGS; ++g) t += lpart[(size_t)g * NROWS + row];
        s += LN2f * log2f(t) - INVT * diag[row];
    }
    for (int m = 1; m < 64; m <<= 1) s += __shfl_xor(s, m, 64);
    int wave = threadIdx.x >> 6, lane = threadIdx.x & 63;
    if (lane == 0) sm[wave] = s;
    __syncthreads();
    if (threadIdx.x == 0) {
        float tot = sm[0] + sm[1] + sm[2] + sm[3];
        atomicAdd(out, tot * (1.0f / NROWS));
    }
}

extern "C" void kernel_launch(void* const* d_in, const int* in_sizes, int n_in,
                              void* d_out, int out_size, void* d_ws, size_t ws_size,
                              hipStream_t stream) {
    const float* fl = (const float*)d_in[0];
    const float* fg = (const float*)d_in[1];
    float* out = (float*)d_out;

    char* ws = (char*)d_ws;
    unsigned char* A = (unsigned char*)ws;                         // 16384*256 = 4 MB
    unsigned char* B = A + (size_t)NROWS * DIM;                    // 4 MB (staging layout)
    float* diag  = (float*)(ws + 2 * (size_t)NROWS * DIM);         // 64 KB
    float* lpart = diag + NROWS;                                   // SEGS*N*4 = 512 KB

    norm_diag_kernel<<<NROWS / 4, 256, 0, stream>>>(fl, fg, A, B, diag, out);
    sim_lse_kernel<<<dim3(SEGS, NROWS / 256), 256, 0, stream>>>(A, B, lpart);
    reduce_kernel<<<32, 256, 0, stream>>>(lpart, diag, out);
}

// Round 23
// 119.109 us; speedup vs baseline: 1.6537x; 1.1657x over previous
//
#include <hip/hip_runtime.h>
#include <hip/hip_bf16.h>

#define NROWS 16384
#define DIM   256
#define DB    (DIM / 2)               // 128 bytes per fp4 row
#define SEGS  8
#define BN    128                     // staged tile: 128 cols x 256 k (fp4) = 16 KB
#define TB    (BN * DB)               // 16384 bytes per staged tile
#define NT    ((NROWS / SEGS) / BN)   // 16 tiles per segment
#define INVT  14.285714285714286f
#define C1f   20.60992915555662f      // log2(e)/0.07 ; A is pre-scaled by this
#define LN2f  0.6931471805599453f

typedef __attribute__((ext_vector_type(8)))  int   int8v;    // MFMA operand (fp4 uses low 4 regs)
typedef __attribute__((ext_vector_type(16))) float f32x16;   // 32x32 MFMA accumulator

#define SCA 0x7F7F7F7Fu   // E8M0 = 2^0   (A scale; A pre-scaled by C1, sigma~1.29)
#define SCB 0x7B7B7B7Bu   // E8M0 = 2^-4  (B scale; B pre-multiplied by 16, sigma~1.0)

// fp4 e2m1 RNE quantize: codes 0..7 = {0, .5, 1, 1.5, 2, 3, 4, 6} (monotonic), bit3 = sign
__device__ __forceinline__ unsigned fp4q(float v) {
    float a = fabsf(v);
    unsigned s = (__float_as_uint(v) >> 28) & 0x8u;
    unsigned idx = (unsigned)(a >= 0.25f) + (a >= 0.75f) + (a >= 1.25f) + (a >= 1.75f)
                 + (a >= 2.5f) + (a >= 3.5f) + (a >= 5.0f);
    return s | idx;
}

// Kernel 1: L2-normalize (fp32); emit fp4 A (row-major, xC1) and fp4 B (x16) in the
// DMA staging layout, plus exact fp32 diagonal. One wave per row; lane holds 4 values
// = 16 bits per matrix.
// B layout (16B chunks of the 128B fp4 row): chunk(col,kcb4) = (col>>7)*1024
//     + ((col>>6)&1)*512 + kcb4*64 + (col&63),   kcb4 = 16B chunk along K (0..7)
__global__ __launch_bounds__(256) void norm_diag_kernel(
    const float* __restrict__ fl, const float* __restrict__ fg,
    unsigned char* __restrict__ A, unsigned char* __restrict__ B,
    float* __restrict__ diag, float* __restrict__ out)
{
    int tid  = threadIdx.x;
    int wave = tid >> 6, lane = tid & 63;
    int row  = blockIdx.x * 4 + wave;
    if (blockIdx.x == 0 && tid == 0) out[0] = 0.0f;   // zero accumulator for final atomicAdd

    float4 xl = ((const float4*)(fl + (size_t)row * DIM))[lane];
    float4 xg = ((const float4*)(fg + (size_t)row * DIM))[lane];
    float ssl = xl.x*xl.x + xl.y*xl.y + xl.z*xl.z + xl.w*xl.w;
    float ssg = xg.x*xg.x + xg.y*xg.y + xg.z*xg.z + xg.w*xg.w;
    for (int m = 1; m < 64; m <<= 1) {
        ssl += __shfl_xor(ssl, m, 64);
        ssg += __shfl_xor(ssg, m, 64);
    }
    float il = 1.0f / fmaxf(sqrtf(ssl), 1e-12f);
    float ig = 1.0f / fmaxf(sqrtf(ssg), 1e-12f);
    float nl0 = xl.x*il, nl1 = xl.y*il, nl2 = xl.z*il, nl3 = xl.w*il;
    float ng0 = xg.x*ig, ng1 = xg.y*ig, ng2 = xg.z*ig, ng3 = xg.w*ig;

    // A: quantize C1*nl to fp4 (scale 2^0 at MFMA); lane holds k = 4*lane..4*lane+3
    unsigned pa4 = fp4q(nl0 * C1f) | (fp4q(nl1 * C1f) << 4)
                 | (fp4q(nl2 * C1f) << 8) | (fp4q(nl3 * C1f) << 12);
    ((unsigned short*)(A + (size_t)row * DB))[lane] = (unsigned short)pa4;

    // B: quantize 16*ng to fp4 (scale 2^-4 at MFMA), store into staging layout
    unsigned pb4 = fp4q(ng0 * 16.0f) | (fp4q(ng1 * 16.0f) << 4)
                 | (fp4q(ng2 * 16.0f) << 8) | (fp4q(ng3 * 16.0f) << 12);
    {
        int kcb4 = lane >> 3;         // 16B chunk along K (0..7); lane's 2 bytes sit at (lane&7)*2
        unsigned chunk = (unsigned)((row >> 7) * 1024 + ((row >> 6) & 1) * 512
                                    + kcb4 * 64 + (row & 63));
        ((unsigned short*)B)[chunk * 8 + (lane & 7)] = (unsigned short)pb4;
    }

    float d = nl0*ng0 + nl1*ng1 + nl2*ng2 + nl3*ng3;   // exact fp32 diagonal
    for (int m = 1; m < 64; m <<= 1) d += __shfl_xor(d, m, 64);
    if (lane == 0) diag[row] = d;
}

// Kernel 2: fused sim-GEMM + fixed-max sumexp, MX-fp4 32x32x64 (fmt=4, 2x fp8 rate).
// R19 frame: DMA prefetch across one barrier/tile, ping-pong acc, deferred epilogue,
// imm-offset LDS reads. fp4 halves MFMA cycles AND LDS/staging bytes; uniform
// power-of-2 scales (A: 2^0 on C1-prescaled data, B: 2^-4 on 16x-prescaled data)
// avoid per-block MX scale machinery entirely.
__global__ __launch_bounds__(256, 2) void sim_lse_kernel(
    const unsigned char* __restrict__ A, const unsigned char* __restrict__ B,
    float* __restrict__ lpart)
{
    __shared__ __align__(16) unsigned char bt[2 * TB];   // 2 x 16 KB double buffer

    int tid  = threadIdx.x;
    int lane = tid & 63;
    int l31  = lane & 31, half = lane >> 5;
    int wave = tid >> 6;
    int seg  = blockIdx.x;
    int rowBase = blockIdx.y * 256 + wave * 64;

    // LDS read base; unit offsets are 16-bit immediates:
    // addr = vb + bufo(16384) + s64*8192 + c*512 + kk*2048
    unsigned vb = (unsigned)(l31 * 16 + half * 1024);

    const int4 zero4 = make_int4(0, 0, 0, 0);

    // Preload A fragments: lane(l31,half) holds A[m=..][k = kk*64 + half*32 + 0..31]
    // = 16 bytes of fp4; high half of the 8-reg operand is unused (fmt=4) -> zeroed once.
    int8v af[2][4];
#pragma unroll
    for (int s = 0; s < 2; ++s) {
        const unsigned char* ap = A + (size_t)(rowBase + s*32 + l31) * DB + half * 16;
#pragma unroll
        for (int kk = 0; kk < 4; ++kk) {
            ((int4*)&af[s][kk])[0] = *(const int4*)(ap + kk * 32);
            ((int4*)&af[s][kk])[1] = zero4;
        }
    }

    f32x16 lv[2];
    f32x16 Z;
    f32x16 accA[2], accB[2];
#pragma unroll
    for (int r = 0; r < 16; ++r) {
        lv[0][r] = -1.0f; lv[1][r] = -1.0f;   // compensate the one dummy epilogue
        Z[r] = 0.0f;
        accB[0][r] = 0.0f; accB[1][r] = 0.0f; // dummy-epilogue source
    }

    int T0 = seg * NT;

    // Stage one 16 KB tile (1024 16B chunks); each thread moves 4 chunks
    auto stage = [&](int T, unsigned bufo) {
        const unsigned char* g = B + (size_t)T * TB + (unsigned)tid * 16;
        unsigned lo = bufo + (unsigned)tid * 16;
#pragma unroll
        for (int j = 0; j < 4; ++j) {
            __builtin_amdgcn_global_load_lds(
                (const __attribute__((address_space(1))) unsigned int*)(g + j * 4096),
                (__attribute__((address_space(3))) unsigned int*)&bt[lo + j * 4096],
                16, 0, 0);
        }
    };

#define MFMA4(dst, a, b, cin) \
    dst = __builtin_amdgcn_mfma_scale_f32_32x32x64_f8f6f4(a, b, cin, 4, 4, 0, SCA, 0, SCB)

    // One 64x32 unit: 4 ds_read_b128 (one per K-step) + 8 MFMAs, 2-deep bf rotation
    auto chain = [&](f32x16 (&ac)[2], unsigned ab, unsigned offc) {
        int8v b0, b1;
        ((int4*)&b0)[1] = zero4; ((int4*)&b1)[1] = zero4;
        ((int4*)&b0)[0] = *(const int4*)&bt[ab + offc];           // kk=0
        ((int4*)&b1)[0] = *(const int4*)&bt[ab + offc + 2048u];   // kk=1
        MFMA4(ac[0], af[0][0], b0, Z);
        MFMA4(ac[1], af[1][0], b0, Z);
        ((int4*)&b0)[0] = *(const int4*)&bt[ab + offc + 4096u];   // kk=2
        MFMA4(ac[0], af[0][1], b1, ac[0]);
        MFMA4(ac[1], af[1][1], b1, ac[1]);
        ((int4*)&b1)[0] = *(const int4*)&bt[ab + offc + 6144u];   // kk=3
        MFMA4(ac[0], af[0][2], b0, ac[0]);
        MFMA4(ac[1], af[1][2], b0, ac[1]);
        MFMA4(ac[0], af[0][3], b1, ac[0]);
        MFMA4(ac[1], af[1][3], b1, ac[1]);
    };

    auto epi = [&](f32x16 (&ac)[2]) {
#pragma unroll
        for (int s = 0; s < 2; ++s) {
            f32x16 e;
#pragma unroll
            for (int r = 0; r < 16; ++r)
                e[r] = __builtin_amdgcn_exp2f(ac[s][r]);
            lv[s] += e;
        }
    };

    stage(T0, 0);

    for (int t = 0; t < NT; ++t) {
        unsigned bufo = (t & 1) ? (unsigned)TB : 0u;
        __syncthreads();   // drains own tile-t DMA (in flight a full tile), syncs waves

        if (t + 1 < NT)
            stage(T0 + t + 1, (t & 1) ? 0u : (unsigned)TB);

        unsigned ab = vb + bufo;
        chain(accA, ab, 0u);     epi(accB);   // cols  0-31 of sub-tile 0
        chain(accB, ab, 512u);   epi(accA);   // cols 32-63
        chain(accA, ab, 8192u);  epi(accB);   // cols 64-95 (sub-tile 1)
        chain(accB, ab, 8704u);  epi(accA);   // cols 96-127
    }
    epi(accB);   // final unit

    // Sum across the 32 column-lanes
#pragma unroll
    for (int s = 0; s < 2; ++s)
#pragma unroll
        for (int r = 0; r < 16; ++r) {
            float v = lv[s][r];
            v += __shfl_xor(v, 1, 64);
            v += __shfl_xor(v, 2, 64);
            v += __shfl_xor(v, 4, 64);
            v += __shfl_xor(v, 8, 64);
            v += __shfl_xor(v, 16, 64);
            lv[s][r] = v;
        }
    if (l31 == 0) {
#pragma unroll
        for (int s = 0; s < 2; ++s)
#pragma unroll
            for (int r = 0; r < 16; ++r) {
                int row = rowBase + s*32 + (r & 3) + 8*(r >> 2) + 4*half;
                lpart[(size_t)seg * NROWS + row] = lv[s][r];
            }
    }
#undef MFMA4
}

// Kernel 3: loss_i = -invT*diag_i + ln2*log2(sum_seg l_part), then mean via atomicAdd.
__global__ __launch_bounds__(256) void reduce_kernel(
    const float* __restrict__ lpart, const float* __restrict__ diag,
    float* __restrict__ out)
{
    __shared__ float sm[4];
    int gtid = blockIdx.x * 256 + threadIdx.x;
    float s = 0.0f;
    for (int row = gtid; row < NROWS; row += 32 * 256) {
        float t = 0.0f;
#pragma unroll
        for (int g = 0; g < SEGS; ++g) t += lpart[(size_t)g * NROWS + row];
        s += LN2f * log2f(t) - INVT * diag[row];
    }
    for (int m = 1; m < 64; m <<= 1) s += __shfl_xor(s, m, 64);
    int wave = threadIdx.x >> 6, lane = threadIdx.x & 63;
    if (lane == 0) sm[wave] = s;
    __syncthreads();
    if (threadIdx.x == 0) {
        float tot = sm[0] + sm[1] + sm[2] + sm[3];
        atomicAdd(out, tot * (1.0f / NROWS));
    }
}

extern "C" void kernel_launch(void* const* d_in, const int* in_sizes, int n_in,
                              void* d_out, int out_size, void* d_ws, size_t ws_size,
                              hipStream_t stream) {
    const float* fl = (const float*)d_in[0];
    const float* fg = (const float*)d_in[1];
    float* out = (float*)d_out;

    char* ws = (char*)d_ws;
    unsigned char* A = (unsigned char*)ws;                         // 16384*128 = 2 MB (fp4)
    unsigned char* B = A + (size_t)NROWS * DB;                     // 2 MB (fp4, staging layout)
    float* diag  = (float*)(ws + 2 * (size_t)NROWS * DB);          // 64 KB
    float* lpart = diag + NROWS;                                   // SEGS*N*4 = 512 KB

    norm_diag_kernel<<<NROWS / 4, 256, 0, stream>>>(fl, fg, A, B, diag, out);
    sim_lse_kernel<<<dim3(SEGS, NROWS / 256), 256, 0, stream>>>(A, B, lpart);
    reduce_kernel<<<32, 256, 0, stream>>>(lpart, diag, out);
}